// Round 1
// baseline (1255.599 us; speedup 1.0000x reference)
//
#include <hip/hip_runtime.h>
#include <math.h>

// Problem constants (from setup_inputs: N=8, C=1, H=W=512, fp32)
#define IMG_H 512
#define IMG_W 512
#define NSAMP 8
#define NIMG  16                 // 8 sigmoid(p) images + 8 target images, skeletonized together
#define PS    (IMG_H * IMG_W)    // per-sample pixels

#define TILE 32
// fused-iteration kernel: radius 3 (erode -> erode -> dilate)
#define HALO 3
#define XS  (TILE + 2*HALO)      // 38  x tile with halo
#define E1S (TILE + 4)           // 36  erode(x) region
#define E2S (TILE + 2)           // 34  erode(erode(x)) region

__device__ __forceinline__ float sigmoidf_dev(float x) {
    return 1.0f / (1.0f + expf(-x));
}

// Pack X[0:8*PS] = sigmoid(logits), X[8*PS:16*PS] = target
__global__ __launch_bounds__(256) void prep_kernel(const float* __restrict__ logits,
                                                   const float* __restrict__ target,
                                                   float* __restrict__ X, int n)
{
    int i = blockIdx.x * 256 + threadIdx.x;
    if (i < n) {
        X[i]     = sigmoidf_dev(logits[i]);
        X[i + n] = target[i];
    }
}

// s = relu(x - dilate(erode(x)))   [radius 2]
__global__ __launch_bounds__(256) void skel_init_kernel(const float* __restrict__ xin,
                                                        float* __restrict__ s)
{
    __shared__ float xt[TILE + 4][TILE + 4 + 2];   // 36x38
    __shared__ float e1[TILE + 2][TILE + 2 + 2];   // 34x36
    const float INF = __builtin_inff();
    const int img = blockIdx.z;
    const int by = blockIdx.y * TILE, bx = blockIdx.x * TILE;
    const float* xi = xin + (size_t)img * PS;
    float* si = s + (size_t)img * PS;
    const int tid = threadIdx.x;
    const int X2 = TILE + 4, E2 = TILE + 2;

    for (int idx = tid; idx < X2 * X2; idx += 256) {
        int i = idx / X2, j = idx % X2;
        int gy = by - 2 + i, gx = bx - 2 + j;
        float v = INF;   // +inf pad: feeds min (erode)
        if (gy >= 0 && gy < IMG_H && gx >= 0 && gx < IMG_W) v = xi[gy * IMG_W + gx];
        xt[i][j] = v;
    }
    __syncthreads();

    for (int idx = tid; idx < E2 * E2; idx += 256) {
        int i = idx / E2 + 1, j = idx % E2 + 1;    // xt coords [1,35)
        int gy = by - 2 + i, gx = bx - 2 + j;
        float v;
        if (gy >= 0 && gy < IMG_H && gx >= 0 && gx < IMG_W) {
            float vm = fminf(fminf(xt[i-1][j], xt[i][j]), xt[i+1][j]);
            float hm = fminf(fminf(xt[i][j-1], xt[i][j]), xt[i][j+1]);
            v = fminf(vm, hm);
        } else {
            v = -INF;    // -inf pad: feeds max (dilate)
        }
        e1[i-1][j-1] = v;
    }
    __syncthreads();

    for (int idx = tid; idx < TILE * TILE; idx += 256) {
        int ty = idx / TILE, tx = idx % TILE;
        int i = ty + 1, j = tx + 1;                // e1 coords of this pixel
        float d = e1[i-1][j-1];
        d = fmaxf(d, e1[i-1][j]);   d = fmaxf(d, e1[i-1][j+1]);
        d = fmaxf(d, e1[i][j-1]);   d = fmaxf(d, e1[i][j]);   d = fmaxf(d, e1[i][j+1]);
        d = fmaxf(d, e1[i+1][j-1]); d = fmaxf(d, e1[i+1][j]); d = fmaxf(d, e1[i+1][j+1]);
        float x = xt[ty + 2][tx + 2];
        si[(size_t)(by + ty) * IMG_W + (bx + tx)] = fmaxf(x - d, 0.0f);
    }
}

// One fused skeleton iteration:
//   e1 = erode(x); e2 = erode(e1); d = dilate(e2)
//   delta = relu(e1 - d); s += relu(delta - s*delta); x_out = e1
__global__ __launch_bounds__(256) void iter_kernel(const float* __restrict__ xin,
                                                   float* __restrict__ xout,
                                                   float* __restrict__ s)
{
    __shared__ float xt[XS][XS + 2];     // 38x40
    __shared__ float e1[E1S][E1S + 2];   // 36x38
    __shared__ float e2[E2S][E2S + 2];   // 34x36
    const float INF = __builtin_inff();
    const int img = blockIdx.z;
    const int by = blockIdx.y * TILE, bx = blockIdx.x * TILE;
    const float* xi = xin + (size_t)img * PS;
    float* xo = xout + (size_t)img * PS;
    float* si = s + (size_t)img * PS;
    const int tid = threadIdx.x;

    // load x with radius-3 halo, +inf outside image (identity for min)
    for (int idx = tid; idx < XS * XS; idx += 256) {
        int i = idx / XS, j = idx % XS;
        int gy = by - HALO + i, gx = bx - HALO + j;
        float v = INF;
        if (gy >= 0 && gy < IMG_H && gx >= 0 && gx < IMG_W) v = xi[gy * IMG_W + gx];
        xt[i][j] = v;
    }
    __syncthreads();

    // e1 = erode(x) on xt coords [1,37); force +inf at out-of-image (feeds min again)
    for (int idx = tid; idx < E1S * E1S; idx += 256) {
        int i = idx / E1S + 1, j = idx % E1S + 1;
        int gy = by - HALO + i, gx = bx - HALO + j;
        float v;
        if (gy >= 0 && gy < IMG_H && gx >= 0 && gx < IMG_W) {
            float vm = fminf(fminf(xt[i-1][j], xt[i][j]), xt[i+1][j]);
            float hm = fminf(fminf(xt[i][j-1], xt[i][j]), xt[i][j+1]);
            v = fminf(vm, hm);
        } else {
            v = INF;
        }
        e1[i-1][j-1] = v;
    }
    __syncthreads();

    // e2 = erode(e1) on e1 coords [1,35); force -inf at out-of-image (feeds max)
    for (int idx = tid; idx < E2S * E2S; idx += 256) {
        int i = idx / E2S + 1, j = idx % E2S + 1;       // e1 coords
        int gy = by + i - 2, gx = bx + j - 2;           // global coords of this cell
        float v;
        if (gy >= 0 && gy < IMG_H && gx >= 0 && gx < IMG_W) {
            float vm = fminf(fminf(e1[i-1][j], e1[i][j]), e1[i+1][j]);
            float hm = fminf(fminf(e1[i][j-1], e1[i][j]), e1[i][j+1]);
            v = fminf(vm, hm);
        } else {
            v = -INF;
        }
        e2[i-1][j-1] = v;
    }
    __syncthreads();

    // dilate + delta + skel update + write x_new (all output pixels are in-bounds: 512 % 32 == 0)
    for (int idx = tid; idx < TILE * TILE; idx += 256) {
        int ty = idx / TILE, tx = idx % TILE;
        int i = ty + 1, j = tx + 1;                     // e2 coords of this pixel
        float d = e2[i-1][j-1];
        d = fmaxf(d, e2[i-1][j]);   d = fmaxf(d, e2[i-1][j+1]);
        d = fmaxf(d, e2[i][j-1]);   d = fmaxf(d, e2[i][j]);   d = fmaxf(d, e2[i][j+1]);
        d = fmaxf(d, e2[i+1][j-1]); d = fmaxf(d, e2[i+1][j]); d = fmaxf(d, e2[i+1][j+1]);
        float e1v = e1[ty + 2][tx + 2];
        float delta = fmaxf(e1v - d, 0.0f);
        size_t g = (size_t)(by + ty) * IMG_W + (bx + tx);
        float sv = si[g];
        sv = sv + fmaxf(delta - sv * delta, 0.0f);
        si[g] = sv;
        xo[g] = e1v;
    }
}

// Per-sample sums: A=sum(sp*t) B=sum(sp) C=sum(sl*p) D=sum(sl) E=sum(p*t) F=sum(p) G=sum(t)
__global__ __launch_bounds__(256) void reduce_kernel(const float* __restrict__ logits,
                                                     const float* __restrict__ target,
                                                     const float* __restrict__ S,
                                                     float* __restrict__ acc)
{
    const int sample = blockIdx.y;
    const size_t base = (size_t)sample * PS;
    const float* Sp = S + base;
    const float* Sl = S + (size_t)NSAMP * PS + base;
    float v[7] = {0.f, 0.f, 0.f, 0.f, 0.f, 0.f, 0.f};
    for (int i = blockIdx.x * 256 + threadIdx.x; i < PS; i += gridDim.x * 256) {
        float p  = sigmoidf_dev(logits[base + i]);
        float t  = target[base + i];
        float sp = Sp[i];
        float sl = Sl[i];
        v[0] += sp * t; v[1] += sp; v[2] += sl * p; v[3] += sl;
        v[4] += p * t;  v[5] += p;  v[6] += t;
    }
    #pragma unroll
    for (int off = 32; off > 0; off >>= 1)
        #pragma unroll
        for (int q = 0; q < 7; q++)
            v[q] += __shfl_down(v[q], off, 64);
    if ((threadIdx.x & 63) == 0)
        #pragma unroll
        for (int q = 0; q < 7; q++)
            atomicAdd(&acc[sample * 7 + q], v[q]);
}

__global__ void final_kernel(const float* __restrict__ acc, float* __restrict__ out)
{
    if (threadIdx.x == 0 && blockIdx.x == 0) {
        float cl = 0.f, dice = 0.f;
        for (int n = 0; n < NSAMP; n++) {
            const float* a = acc + n * 7;
            float A = a[0], B = a[1], C = a[2], D = a[3], E = a[4], F = a[5], G = a[6];
            float tprec = (A + 1.0f) / (B + 1.0f);
            float tsens = (C + 1.0f) / (D + 1.0f);
            cl   += 1.0f - 2.0f * tprec * tsens / (tprec + tsens);
            dice += 1.0f - 2.0f * (E + 1.0f) / (F + G + 1.0f);
        }
        cl   *= (1.0f / NSAMP);
        dice *= (1.0f / NSAMP);
        out[0] = 0.7f * dice + 0.3f * cl;
    }
}

extern "C" void kernel_launch(void* const* d_in, const int* in_sizes, int n_in,
                              void* d_out, int out_size, void* d_ws, size_t ws_size,
                              hipStream_t stream)
{
    const float* logits = (const float*)d_in[0];   // "output" (8,1,512,512) fp32
    const float* target = (const float*)d_in[1];   // "target" (8,1,512,512) fp32
    float* out = (float*)d_out;

    const size_t NTOT = (size_t)NIMG * PS;         // 4,194,304 floats = 16 MB
    float* Xa  = (float*)d_ws;                     // ws layout: Xa | Xb | S | acc  (~48 MB)
    float* Xb  = Xa + NTOT;
    float* S   = Xb + NTOT;
    float* acc = S + NTOT;                         // 8 samples x 7 sums

    hipMemsetAsync(acc, 0, NSAMP * 7 * sizeof(float), stream);

    const int n = NSAMP * PS;                      // 2,097,152
    prep_kernel<<<n / 256, 256, 0, stream>>>(logits, target, Xa, n);

    dim3 grid(IMG_W / TILE, IMG_H / TILE, NIMG);   // (16,16,16)
    skel_init_kernel<<<grid, 256, 0, stream>>>(Xa, S);

    float* xin = Xa;
    float* xout = Xb;
    for (int it = 0; it < 50; it++) {
        iter_kernel<<<grid, 256, 0, stream>>>(xin, xout, S);
        float* t = xin; xin = xout; xout = t;
    }

    reduce_kernel<<<dim3(64, NSAMP), 256, 0, stream>>>(logits, target, S, acc);
    final_kernel<<<1, 64, 0, stream>>>(acc, out);
}

// Round 2
// 436.660 us; speedup vs baseline: 2.8755x; 2.8755x over previous
//
#include <hip/hip_runtime.h>
#include <math.h>

// Problem: N=8, C=1, H=W=512 fp32. 16 images (8 sigmoid + 8 target) skeletonized.
#define IMG   512
#define NSAMP 8
#define NIMG  16
#define PS    (IMG * IMG)

#define T   64     // output tile
#define HL  12     // halo (supports up to c=11 fused levels)
#define BW  88     // buffer rows/cols = T + 2*HL
#define BST 92     // row stride in floats (368 B = 23*16, keeps rows 16B aligned)

__device__ __forceinline__ float sigm(float x) { return 1.0f / (1.0f + expf(-x)); }

// ---- prep: X[0:n]=sigmoid(logits), X[n:2n]=target, S=0 ----
__global__ __launch_bounds__(256) void prep_kernel(const float4* __restrict__ lg,
                                                   const float4* __restrict__ tg,
                                                   float4* __restrict__ X,
                                                   float4* __restrict__ S, int n4)
{
    int i = blockIdx.x * 256 + threadIdx.x;
    if (i < n4) {
        float4 L = lg[i];
        float4 p = make_float4(sigm(L.x), sigm(L.y), sigm(L.z), sigm(L.w));
        X[i]      = p;
        X[i + n4] = tg[i];
        float4 z = make_float4(0.f, 0.f, 0.f, 0.f);
        S[i]      = z;
        S[i + n4] = z;
    }
}

// ---- fused k-level skeleton kernel ----
// Per level j: x_{j+1} = erode(x_j) (cross-min, OOB=+inf);
//              delta_j = relu(x_j - dilate3x3(x_{j+1})) (OOB=-inf);
//              skel += relu(delta - skel*delta)  [skel in registers]
__global__ __launch_bounds__(256) void fused_kernel(const float* __restrict__ xin,
                                                    float* __restrict__ xout,
                                                    float* __restrict__ S, int c)
{
    __shared__ __align__(16) float bufA[BW * BST];
    __shared__ __align__(16) float bufB[BW * BST];
    const float INF = __builtin_inff();
    const int tid = threadIdx.x;
    const int img = blockIdx.z;
    const int oy = blockIdx.y * T, ox = blockIdx.x * T;  // tile origin (global)
    const int by = oy - HL, bx = ox - HL;                // buffer origin (global)

    const float* xi = xin + (size_t)img * PS;

    // load x0 (88x88), +inf outside image
    for (int idx = tid; idx < BW * BW; idx += 256) {
        int r = idx / BW, cc = idx - r * BW;
        int gy = by + r, gx = bx + cc;
        float v = INF;
        if ((unsigned)gy < IMG && (unsigned)gx < IMG) v = xi[gy * IMG + gx];
        bufA[r * BST + cc] = v;
    }

    // fixed output mapping for dilate/skel/output: 16x16 threads, 4x4 px each
    const int s = tid & 15, b = tid >> 4;
    float4 sk[4];
    {
        const float4* Sg = (const float4*)(S + (size_t)img * PS);
        #pragma unroll
        for (int rr = 0; rr < 4; ++rr)
            sk[rr] = Sg[((oy + 4 * b + rr) * IMG + ox + 4 * s) >> 2];
    }
    __syncthreads();

    float* A = bufA;
    float* B = bufB;

    // erode mapping: 22 col-segments x 11 row-strips (242 active threads)
    const int s2 = tid % 22, b2 = tid / 22;
    const int ec0 = 4 * s2;                         // output cols ec0..ec0+3 (0..87)
    const int offL = (s2 == 0) ? 0 : -1;            // avoid negative LDS index at col 0 (ring cell, garbage ok)
    bool ecoob[4];
    #pragma unroll
    for (int k = 0; k < 4; ++k) ecoob[k] = ((unsigned)(bx + ec0 + k) >= IMG);
    // dilate edge-column flags
    const bool dcl = (ox + 4 * s - 1) < 0;
    const bool dcr = (ox + 4 * s + 4) > (IMG - 1);

    for (int j = 0; j < c; ++j) {
        // ---- erode A -> B on rows [1,87), cols [0,88) ----
        if (b2 < 11) {
            int rs = 1 + 8 * b2;
            int re = (rs + 8 < 87) ? (rs + 8) : 87;
            float aL, a0, a1, a2, a3;
            float bL, b0, b1, b2v, b3, bR;
            float cL, c0, c1, c2, c3, cR;
            {
                const float* p = A + (rs - 1) * BST + ec0;
                aL = p[offL];
                float4 m = *(const float4*)p;
                a0 = m.x; a1 = m.y; a2 = m.z; a3 = m.w;
                p = A + rs * BST + ec0;
                bL = p[offL];
                m = *(const float4*)p;  bR = p[4];
                b0 = m.x; b1 = m.y; b2v = m.z; b3 = m.w;
            }
            for (int r = rs; r < re; ++r) {
                const float* p = A + (r + 1) * BST + ec0;
                cL = p[offL];
                float4 m = *(const float4*)p;  cR = p[4];
                c0 = m.x; c1 = m.y; c2 = m.z; c3 = m.w;
                bool roob = ((unsigned)(by + r) >= IMG);
                float e0 = fminf(fminf(fminf(a0, b0), c0), fminf(bL,  b1));
                float e1 = fminf(fminf(fminf(a1, b1), c1), fminf(b0,  b2v));
                float e2 = fminf(fminf(fminf(a2, b2v), c2), fminf(b1, b3));
                float e3 = fminf(fminf(fminf(a3, b3), c3), fminf(b2v, bR));
                e0 = (roob | ecoob[0]) ? INF : e0;
                e1 = (roob | ecoob[1]) ? INF : e1;
                e2 = (roob | ecoob[2]) ? INF : e2;
                e3 = (roob | ecoob[3]) ? INF : e3;
                *(float4*)(B + r * BST + ec0) = make_float4(e0, e1, e2, e3);
                aL = bL; a0 = b0; a1 = b1; a2 = b2v; a3 = b3;
                bL = cL; b0 = c0; b1 = c1; b2v = c2; b3 = c3; bR = cR;
            }
        }
        __syncthreads();

        // ---- dilate(B) + delta from A + skel update (output tile only) ----
        {
            const int CB = 11 + 4 * s;   // span cols CB..CB+5 (global ox+4s-1 .. ox+4s+4)
            float r0[6], r1[6], r2[6];
            auto loadrow = [&](int k, float* d) {
                const float* p = B + (11 + 4 * b + k) * BST + CB;
                d[0] = p[0];
                float4 m = *(const float4*)(p + 1);   // col CB+1 = 12+4s -> 16B aligned
                d[1] = m.x; d[2] = m.y; d[3] = m.z; d[4] = m.w;
                d[5] = p[5];
                int grow = oy + 4 * b - 1 + k;
                if ((unsigned)grow >= IMG) {
                    #pragma unroll
                    for (int q = 0; q < 6; ++q) d[q] = -INF;
                } else {
                    if (dcl) d[0] = -INF;
                    if (dcr) d[5] = -INF;
                }
            };
            loadrow(0, r0); loadrow(1, r1); loadrow(2, r2);
            float* ra = r0; float* rb = r1; float* rc = r2;
            #pragma unroll
            for (int rr = 0; rr < 4; ++rr) {
                float vm[6];
                #pragma unroll
                for (int q = 0; q < 6; ++q) vm[q] = fmaxf(fmaxf(ra[q], rb[q]), rc[q]);
                float d0 = fmaxf(fmaxf(vm[0], vm[1]), vm[2]);
                float d1 = fmaxf(fmaxf(vm[1], vm[2]), vm[3]);
                float d2 = fmaxf(fmaxf(vm[2], vm[3]), vm[4]);
                float d3 = fmaxf(fmaxf(vm[3], vm[4]), vm[5]);
                const float4 xj = *(const float4*)(A + (12 + 4 * b + rr) * BST + 12 + 4 * s);
                float t0 = fmaxf(xj.x - d0, 0.f);
                float t1 = fmaxf(xj.y - d1, 0.f);
                float t2 = fmaxf(xj.z - d2, 0.f);
                float t3 = fmaxf(xj.w - d3, 0.f);
                sk[rr].x += fmaxf(t0 - sk[rr].x * t0, 0.f);
                sk[rr].y += fmaxf(t1 - sk[rr].y * t1, 0.f);
                sk[rr].z += fmaxf(t2 - sk[rr].z * t2, 0.f);
                sk[rr].w += fmaxf(t3 - sk[rr].w * t3, 0.f);
                if (rr < 3) { float* t = ra; ra = rb; rb = rc; rc = t; loadrow(rr + 3, rc); }
            }
        }
        __syncthreads();
        float* t = A; A = B; B = t;
    }

    // write x_c (now in A) center + skel
    {
        float* Og = xout + (size_t)img * PS;
        float4* Sg = (float4*)(S + (size_t)img * PS);
        #pragma unroll
        for (int rr = 0; rr < 4; ++rr) {
            float4 xv = *(const float4*)(A + (12 + 4 * b + rr) * BST + 12 + 4 * s);
            int gidx = (oy + 4 * b + rr) * IMG + ox + 4 * s;
            *(float4*)(Og + gidx) = xv;
            Sg[gidx >> 2] = sk[rr];
        }
    }
}

// ---- reduction: per-block partials, no global atomics ----
// A=sum(sp*t) B=sum(sp) C=sum(sl*p) D=sum(sl) E=sum(p*t) F=sum(p) G=sum(t)
__global__ __launch_bounds__(256) void reduce_kernel(const float* __restrict__ logits,
                                                     const float* __restrict__ target,
                                                     const float* __restrict__ S,
                                                     float* __restrict__ partial)
{
    const int sample = blockIdx.y;
    const size_t base = (size_t)sample * PS;
    const float4* p4  = (const float4*)(logits + base);
    const float4* t4  = (const float4*)(target + base);
    const float4* sp4 = (const float4*)(S + base);
    const float4* sl4 = (const float4*)(S + (size_t)NSAMP * PS + base);
    float v[7] = {0.f, 0.f, 0.f, 0.f, 0.f, 0.f, 0.f};
    const int n4 = PS / 4;
    for (int i = blockIdx.x * 256 + threadIdx.x; i < n4; i += 32 * 256) {
        float4 L = p4[i], Tt = t4[i], SP = sp4[i], SL = sl4[i];
        float p;
        p = sigm(L.x); v[0] += SP.x * Tt.x; v[1] += SP.x; v[2] += SL.x * p; v[3] += SL.x; v[4] += p * Tt.x; v[5] += p; v[6] += Tt.x;
        p = sigm(L.y); v[0] += SP.y * Tt.y; v[1] += SP.y; v[2] += SL.y * p; v[3] += SL.y; v[4] += p * Tt.y; v[5] += p; v[6] += Tt.y;
        p = sigm(L.z); v[0] += SP.z * Tt.z; v[1] += SP.z; v[2] += SL.z * p; v[3] += SL.z; v[4] += p * Tt.z; v[5] += p; v[6] += Tt.z;
        p = sigm(L.w); v[0] += SP.w * Tt.w; v[1] += SP.w; v[2] += SL.w * p; v[3] += SL.w; v[4] += p * Tt.w; v[5] += p; v[6] += Tt.w;
    }
    #pragma unroll
    for (int off = 32; off > 0; off >>= 1)
        #pragma unroll
        for (int q = 0; q < 7; ++q) v[q] += __shfl_down(v[q], off);
    __shared__ float wred[4][7];
    int lane = threadIdx.x & 63, w = threadIdx.x >> 6;
    if (lane == 0)
        #pragma unroll
        for (int q = 0; q < 7; ++q) wred[w][q] = v[q];
    __syncthreads();
    if (threadIdx.x == 0) {
        #pragma unroll
        for (int q = 0; q < 7; ++q)
            partial[(sample * 32 + blockIdx.x) * 7 + q] =
                wred[0][q] + wred[1][q] + wred[2][q] + wred[3][q];
    }
}

__global__ __launch_bounds__(256) void final_kernel(const float* __restrict__ partial,
                                                    float* __restrict__ out)
{
    // 256 threads: thread t -> (sample = t>>5, part = t&31)
    const int t = threadIdx.x;
    const int sample = t >> 5, part = t & 31;
    float v[7];
    #pragma unroll
    for (int q = 0; q < 7; ++q) v[q] = partial[(sample * 32 + part) * 7 + q];
    #pragma unroll
    for (int off = 16; off > 0; off >>= 1)
        #pragma unroll
        for (int q = 0; q < 7; ++q) v[q] += __shfl_down(v[q], off, 32);
    __shared__ float acc[NSAMP][7];
    if (part == 0)
        #pragma unroll
        for (int q = 0; q < 7; ++q) acc[sample][q] = v[q];
    __syncthreads();
    if (t == 0) {
        float cl = 0.f, dice = 0.f;
        for (int n = 0; n < NSAMP; n++) {
            float A = acc[n][0], B = acc[n][1], C = acc[n][2], D = acc[n][3];
            float E = acc[n][4], F = acc[n][5], G = acc[n][6];
            float tprec = (A + 1.0f) / (B + 1.0f);
            float tsens = (C + 1.0f) / (D + 1.0f);
            cl   += 1.0f - 2.0f * tprec * tsens / (tprec + tsens);
            dice += 1.0f - 2.0f * (E + 1.0f) / (F + G + 1.0f);
        }
        out[0] = 0.7f * (dice / NSAMP) + 0.3f * (cl / NSAMP);
    }
}

extern "C" void kernel_launch(void* const* d_in, const int* in_sizes, int n_in,
                              void* d_out, int out_size, void* d_ws, size_t ws_size,
                              hipStream_t stream)
{
    const float* logits = (const float*)d_in[0];
    const float* target = (const float*)d_in[1];
    float* out = (float*)d_out;

    const size_t NTOT = (size_t)NIMG * PS;          // 4,194,304 floats
    float* Xa = (float*)d_ws;                       // Xa | Xb | S | partial
    float* Xb = Xa + NTOT;
    float* S  = Xb + NTOT;
    float* partial = S + NTOT;                      // 256*7 floats

    const int n4 = (NSAMP * PS) / 4;                // 524288
    prep_kernel<<<n4 / 256, 256, 0, stream>>>((const float4*)logits, (const float4*)target,
                                              (float4*)Xa, (float4*)S, n4);

    dim3 grid(IMG / T, IMG / T, NIMG);              // (8,8,16)
    // 51 pipeline updates total: c = 11 + 4*10
    fused_kernel<<<grid, 256, 0, stream>>>(Xa, Xb, S, 11);
    fused_kernel<<<grid, 256, 0, stream>>>(Xb, Xa, S, 10);
    fused_kernel<<<grid, 256, 0, stream>>>(Xa, Xb, S, 10);
    fused_kernel<<<grid, 256, 0, stream>>>(Xb, Xa, S, 10);
    fused_kernel<<<grid, 256, 0, stream>>>(Xa, Xb, S, 10);

    reduce_kernel<<<dim3(32, NSAMP), 256, 0, stream>>>(logits, target, S, partial);
    final_kernel<<<1, 256, 0, stream>>>(partial, out);
}